// Round 2
// baseline (638.587 us; speedup 1.0000x reference)
//
#include <hip/hip_runtime.h>
#include <hip/hip_bf16.h>

// ---------------------------------------------------------------------------
// UpsdHyper round 2.
// Y[b,o] = Σ_d c[b,d]·(Σ_h act[b,h]·W[d,h,o]) + Σ_h act[b,h]·hwb[h,o] + bias
// gemm: tile M=512 x N=32, K-step 64. 8 waves, wave-tile 64x32.
// grid (16 n-tiles, 32 d-groups) = 512 blocks = 2 blocks/CU (VGPR<=128 via
// __launch_bounds__(512,4)) so barrier/vmcnt stalls overlap across blocks.
// Single barrier per iteration; loads issued 2 tiles ahead.
// ---------------------------------------------------------------------------

typedef __bf16 bf16x8 __attribute__((ext_vector_type(8)));
typedef float  f32x4  __attribute__((ext_vector_type(4)));

#define PITCH 72   // 144B rows: 16B-aligned for ds_read_b128, bank-spread

// ---------------------------------------------------------------------------
// embed: act0 = bf16(tanh(state @ embed_w + embed_b))   [512,512]
// ---------------------------------------------------------------------------
__global__ __launch_bounds__(512) void embed_kernel(
    const float* __restrict__ state,   // [512,256]
    const float* __restrict__ ew,      // [256,512]
    const float* __restrict__ eb,      // [512]
    __bf16* __restrict__ act0)         // [512,512] bf16
{
    const int o  = threadIdx.x;
    const int r0 = blockIdx.x * 2;
    float b  = eb[o];
    float a0 = b, a1 = b;
    for (int s = 0; s < 256; ++s) {
        float wv = ew[s * 512 + o];
        a0 = fmaf(state[r0 * 256 + s],       wv, a0);
        a1 = fmaf(state[(r0 + 1) * 256 + s], wv, a1);
    }
    act0[r0 * 512 + o]       = (__bf16)tanhf(a0);
    act0[(r0 + 1) * 512 + o] = (__bf16)tanhf(a1);
}

// ---------------------------------------------------------------------------
// Main hyper-GEMM. Block = (nt 0..15, g 0..31). Tile 512m x 32o, K-step 64h.
// Groups g<8 do one extra iteration adding the hw_b GEMM term (scale=1).
// Writes partial[g][512][32-col slice].
// ---------------------------------------------------------------------------
__global__ __launch_bounds__(512, 4) void hyper_gemm(
    const float* __restrict__ Wl,      // layer base of hw_W: [128][512][512]
    const float* __restrict__ hwbl,    // layer base of hw_b: [512][512] (h,o)
    const float* __restrict__ cmd,     // command [512][128]
    const __bf16* __restrict__ act,    // [512][512] bf16
    float* __restrict__ partial)       // [32][512][512]
{
    __shared__ __bf16 lds[2][32][PITCH];   // Wt[o][h] transposed, bf16

    const int nt   = blockIdx.x;        // 0..15
    const int g    = blockIdx.y;        // 0..31
    const int n0   = nt * 32;
    const int tid  = threadIdx.x;
    const int lane = tid & 63;
    const int wv   = tid >> 6;          // wave 0..7, rows [wv*64, wv*64+64)
    const int l15  = lane & 15;
    const int lg   = lane >> 4;
    const int m_base = wv * 64;

    const int so = (tid & 7) * 4;       // staging o-col group
    const int sh = tid >> 3;            // staging h-row 0..63

    const int nit = 32 + (g < 8 ? 1 : 0);

    f32x4 Y[4][2], G[4][2];
    #pragma unroll
    for (int a = 0; a < 4; ++a)
        #pragma unroll
        for (int b = 0; b < 2; ++b) { Y[a][b] = (f32x4)0.f; G[a][b] = (f32x4)0.f; }

    // tile j address: j<32 -> W[d = g*4 + j/8, h0 = (j%8)*64]; j==32 -> hwb
    #define TILE_PTR(j) ((j) < 32 \
        ? Wl + (size_t)((g << 2) + ((j) >> 3)) * 262144 + (size_t)(((j) & 7) << 6) * 512 + n0 \
        : hwbl + (size_t)(g << 6) * 512 + n0)

    // ---- prologue: stage tile 0, load tile 1 ----
    f32x4 na = *(const f32x4*)(TILE_PTR(0) + sh * 512 + so);
    #pragma unroll
    for (int q = 0; q < 4; ++q) lds[0][so + q][sh] = (__bf16)na[q];
    na = *(const f32x4*)(TILE_PTR(1) + sh * 512 + so);

    int cur = 0;
    for (int i = 0; i < nit; ++i) {
        __syncthreads();   // buf[cur] visible; prev iter's reads of cur^1 done

        // write tile i+1 into the other buffer (data loaded 1 iter ago)
        if (i + 1 < nit) {
            #pragma unroll
            for (int q = 0; q < 4; ++q) lds[cur ^ 1][so + q][sh] = (__bf16)na[q];
        }
        // issue loads for tile i+2 (lands before iteration i+1's writes)
        if (i + 2 < nit)
            na = *(const f32x4*)(TILE_PTR(i + 2) + sh * 512 + so);

        const int h0 = (i < 32) ? ((i & 7) << 6) : (g << 6);

        // ---- compute current tile from lds[cur] ----
        #pragma unroll
        for (int kk = 0; kk < 2; ++kk) {
            bf16x8 afr[4], bfr[2];
            #pragma unroll
            for (int mi = 0; mi < 4; ++mi)
                afr[mi] = *(const bf16x8*)(act + (m_base + mi * 16 + l15) * 512
                                               + h0 + kk * 32 + lg * 8);
            #pragma unroll
            for (int ni = 0; ni < 2; ++ni)
                bfr[ni] = *(const bf16x8*)(&lds[cur][ni * 16 + l15][kk * 32 + lg * 8]);
            #pragma unroll
            for (int mi = 0; mi < 4; ++mi)
                #pragma unroll
                for (int ni = 0; ni < 2; ++ni)
                    G[mi][ni] = __builtin_amdgcn_mfma_f32_16x16x32_bf16(
                        afr[mi], bfr[ni], G[mi][ni], 0, 0, 0);
        }

        // ---- d-boundary: Y += c[m,d] * G ; G = 0 ----
        if (i < 32) {
            if ((i & 7) == 7) {
                const int d = (g << 2) + (i >> 3);
                #pragma unroll
                for (int mi = 0; mi < 4; ++mi) {
                    #pragma unroll
                    for (int r = 0; r < 4; ++r) {
                        float cvv = cmd[(m_base + mi * 16 + lg * 4 + r) * 128 + d];
                        #pragma unroll
                        for (int ni = 0; ni < 2; ++ni) {
                            Y[mi][ni][r] = fmaf(cvv, G[mi][ni][r], Y[mi][ni][r]);
                            G[mi][ni][r] = 0.f;
                        }
                    }
                }
            }
        } else {  // hw_b extra iteration: scale = 1
            #pragma unroll
            for (int mi = 0; mi < 4; ++mi)
                #pragma unroll
                for (int ni = 0; ni < 2; ++ni)
                    #pragma unroll
                    for (int r = 0; r < 4; ++r)
                        Y[mi][ni][r] += G[mi][ni][r];
        }
        cur ^= 1;
    }
    #undef TILE_PTR

    // ---- write partial[g] (exclusive slice: all m, cols n0..n0+31) ----
    float* pp = partial + (size_t)g * 262144 + n0;
    #pragma unroll
    for (int mi = 0; mi < 4; ++mi)
        #pragma unroll
        for (int r = 0; r < 4; ++r) {
            int m = m_base + mi * 16 + lg * 4 + r;
            #pragma unroll
            for (int ni = 0; ni < 2; ++ni)
                pp[m * 512 + ni * 16 + l15] = Y[mi][ni][r];
        }
}

// ---------------------------------------------------------------------------
// epilogue: out = relu(Σ_g partial[g] + c@hb_W + hb_b)
// grid 512 x 512thr: 1 row/block, thread = column.
// ---------------------------------------------------------------------------
__global__ __launch_bounds__(512) void epilogue_kernel(
    const float* __restrict__ partial,   // [32][512][512]
    const float* __restrict__ cmd,       // [512][128]
    const float* __restrict__ hbWl,      // layer base of hb_W: [128][512]
    const float* __restrict__ hbbl,      // layer base of hb_b: [512]
    __bf16* __restrict__ act_out,        // next-layer activation (or null)
    float* __restrict__ final_out)       // final output (or null)
{
    const int o = threadIdx.x;
    const int r = blockIdx.x;
    float a = hbbl[o];
    for (int d = 0; d < 128; ++d)
        a = fmaf(cmd[r * 128 + d], hbWl[d * 512 + o], a);
    float s0 = 0.f, s1 = 0.f, s2 = 0.f, s3 = 0.f;
    #pragma unroll
    for (int gq = 0; gq < 32; gq += 4) {
        s0 += partial[((size_t)(gq + 0) * 512 + r) * 512 + o];
        s1 += partial[((size_t)(gq + 1) * 512 + r) * 512 + o];
        s2 += partial[((size_t)(gq + 2) * 512 + r) * 512 + o];
        s3 += partial[((size_t)(gq + 3) * 512 + r) * 512 + o];
    }
    a = fmaxf(a + (s0 + s1) + (s2 + s3), 0.f);
    if (act_out) act_out[r * 512 + o] = (__bf16)a;
    else         final_out[r * 512 + o] = a;
}

// ---------------------------------------------------------------------------
extern "C" void kernel_launch(void* const* d_in, const int* in_sizes, int n_in,
                              void* d_out, int out_size, void* d_ws, size_t ws_size,
                              hipStream_t stream) {
    const float* state = (const float*)d_in[0];   // [512,256]
    const float* cmd   = (const float*)d_in[1];   // [512,128]
    const float* ew    = (const float*)d_in[2];   // [256,512]
    const float* eb    = (const float*)d_in[3];   // [512]
    const float* hwW   = (const float*)d_in[4];   // [2,128,262144]
    const float* hwb   = (const float*)d_in[5];   // [2,262144]
    const float* hbW   = (const float*)d_in[6];   // [2,128,512]
    const float* hbb   = (const float*)d_in[7];   // [2,512]
    float* out = (float*)d_out;

    char* ws = (char*)d_ws;
    __bf16* act0    = (__bf16*)ws;                       // 512 KB
    __bf16* act1    = (__bf16*)(ws + 512 * 1024);        // 512 KB
    float*  partial = (float*)(ws + 1024 * 1024);        // 32 MB

    embed_kernel<<<256, 512, 0, stream>>>(state, ew, eb, act0);

    // layer 0
    hyper_gemm<<<dim3(16, 32), 512, 0, stream>>>(hwW, hwb, cmd, act0, partial);
    epilogue_kernel<<<512, 512, 0, stream>>>(partial, cmd, hbW, hbb, act1, nullptr);

    // layer 1
    hyper_gemm<<<dim3(16, 32), 512, 0, stream>>>(
        hwW + (size_t)128 * 262144, hwb + 262144, cmd, act1, partial);
    epilogue_kernel<<<512, 512, 0, stream>>>(
        partial, cmd, hbW + 128 * 512, hbb + 512, nullptr, out);
}

// Round 3
// 464.258 us; speedup vs baseline: 1.3755x; 1.3755x over previous
//
#include <hip/hip_runtime.h>
#include <hip/hip_bf16.h>

// ---------------------------------------------------------------------------
// UpsdHyper round 3.
// Y[b,o] = Σ_d c[b,d]·(Σ_h act[b,h]·W[d,h,o]) + Σ_h act[b,h]·hwb[h,o]
//        + Σ_d c[b,d]·hbW[d,o] + hbb[o]      (relu at the end)
//
// hyper_gemm: tile M=512 x N=32, K-step 64h, h-outer/d-inner (4 d per block).
// Counted-vmcnt software pipeline (depth 3), raw s_barrier (no vmcnt drain),
// 4 LDS buffers (buffer index == d-phase). act fragments re-loaded once per
// h-block (4 tiles). hbW/hbb folded into the gemm epilogue; reduce kernel is
// a pure 32-way partial sum + relu.
// ---------------------------------------------------------------------------

typedef __bf16 bf16x8 __attribute__((ext_vector_type(8)));
typedef __bf16 bf16x4 __attribute__((ext_vector_type(4)));
typedef float  f32x4  __attribute__((ext_vector_type(4)));

#define SB() __builtin_amdgcn_sched_barrier(0)
#define VMW_(N) asm volatile("s_waitcnt vmcnt(" #N ")" ::: "memory")
#define VMW(N) do { SB(); VMW_(N); SB(); } while (0)
#define LGKM0() do { SB(); asm volatile("s_waitcnt lgkmcnt(0)" ::: "memory"); SB(); } while (0)

// ---------------------------------------------------------------------------
// embed: act0 = bf16(tanh(state @ embed_w + embed_b))   [512,512]
// ---------------------------------------------------------------------------
__global__ __launch_bounds__(512) void embed_kernel(
    const float* __restrict__ state,   // [512,256]
    const float* __restrict__ ew,      // [256,512]
    const float* __restrict__ eb,      // [512]
    __bf16* __restrict__ act0)         // [512,512] bf16
{
    const int o  = threadIdx.x;
    const int r0 = blockIdx.x * 4;
    float b = eb[o];
    float acc[4] = {b, b, b, b};
    #pragma unroll 4
    for (int s = 0; s < 256; ++s) {
        float wv = ew[s * 512 + o];
        #pragma unroll
        for (int j = 0; j < 4; ++j)
            acc[j] = fmaf(state[(r0 + j) * 256 + s], wv, acc[j]);
    }
    #pragma unroll
    for (int j = 0; j < 4; ++j)
        act0[(r0 + j) * 512 + o] = (__bf16)tanhf(acc[j]);
}

// ---------------------------------------------------------------------------
// Main hyper-GEMM.  Block = (nt 0..15, g 0..31).  8 waves, wave-tile 64m x 32o.
// Tiles t = hb*4 + dl (hb 0..7 h-blocks of 64, dl 0..3 local d).  33rd tile
// (g<8) adds the hw_b term for h-range g*64..g*64+63.
// ---------------------------------------------------------------------------
__global__ __launch_bounds__(512) void hyper_gemm(
    const float* __restrict__ Wl,      // layer base hw_W: [128][512][512]
    const float* __restrict__ hwbl,    // layer base hw_b: [512][512] (h,o)
    const float* __restrict__ cmd,     // command [512][128]
    const float* __restrict__ hbWl,    // layer base hb_W: [128][512]
    const float* __restrict__ hbbl,    // layer base hb_b: [512]
    const __bf16* __restrict__ act,    // [512][512] bf16
    float* __restrict__ partial)       // [32][512][512]
{
    __shared__ __bf16 lw[4][32][72];   // W^T tiles: [buf][o][h], 144B rows
    __shared__ float  lcmd[4][512];    // c[m, g*4+dl] by [dl][m]

    const int nt = blockIdx.x;         // 0..15
    const int g  = blockIdx.y;         // 0..31
    const int n0 = nt * 32, g4 = g << 2;
    const int tid = threadIdx.x, lane = tid & 63, wv = tid >> 6;
    const int l15 = lane & 15, lg = lane >> 4;
    const int m_base = wv << 6;
    const int sh = tid >> 3;           // staging h-row 0..63
    const int so = (tid & 7) << 2;     // staging o-col group

    const float*  wbase = Wl + (size_t)sh * 512 + n0 + so;
    const __bf16* actb  = act + (size_t)(m_base + l15) * 512 + lg * 8;

    f32x4 w_in[4];
    bf16x8 afr[4][2];
    f32x4 Y[4][2];
    const f32x4 z4 = {0.f, 0.f, 0.f, 0.f};
    #pragma unroll
    for (int mi = 0; mi < 4; ++mi)
        #pragma unroll
        for (int ni = 0; ni < 2; ++ni) Y[mi][ni] = z4;

#define LOAD_W(DL_, HB_) \
    w_in[DL_] = *(const f32x4*)(wbase + (size_t)(g4 + (DL_)) * 262144 + (size_t)(HB_) * 32768)

#define STAGE_W(BUF_) do { \
    _Pragma("unroll") \
    for (int q_ = 0; q_ < 4; ++q_) \
        lw[BUF_][so + q_][sh] = (__bf16)w_in[BUF_][q_]; \
} while (0)

#define LOAD_AFR(HB_) do { \
    _Pragma("unroll") \
    for (int mi_ = 0; mi_ < 4; ++mi_) { \
        afr[mi_][0] = *(const bf16x8*)(actb + mi_ * 8192 + (HB_) * 64); \
        afr[mi_][1] = *(const bf16x8*)(actb + mi_ * 8192 + (HB_) * 64 + 32); \
    } \
} while (0)

#define COMPUTE(BUF_, SCALED_) do { \
    _Pragma("unroll") \
    for (int ni_ = 0; ni_ < 2; ++ni_) { \
        bf16x8 b0_ = *(const bf16x8*)&lw[BUF_][ni_ * 16 + l15][lg * 8]; \
        bf16x8 b1_ = *(const bf16x8*)&lw[BUF_][ni_ * 16 + l15][32 + lg * 8]; \
        f32x4 G_[4]; \
        _Pragma("unroll") \
        for (int mi_ = 0; mi_ < 4; ++mi_) \
            G_[mi_] = __builtin_amdgcn_mfma_f32_16x16x32_bf16(afr[mi_][0], b0_, z4, 0, 0, 0); \
        _Pragma("unroll") \
        for (int mi_ = 0; mi_ < 4; ++mi_) \
            G_[mi_] = __builtin_amdgcn_mfma_f32_16x16x32_bf16(afr[mi_][1], b1_, G_[mi_], 0, 0, 0); \
        _Pragma("unroll") \
        for (int mi_ = 0; mi_ < 4; ++mi_) { \
            if (SCALED_) { \
                f32x4 cv_ = *(const f32x4*)&lcmd[BUF_][m_base + mi_ * 16 + lg * 4]; \
                _Pragma("unroll") \
                for (int r_ = 0; r_ < 4; ++r_) \
                    Y[mi_][ni_][r_] = fmaf(cv_[r_], G_[mi_][r_], Y[mi_][ni_][r_]); \
            } else { \
                _Pragma("unroll") \
                for (int r_ = 0; r_ < 4; ++r_) \
                    Y[mi_][ni_][r_] += G_[mi_][r_]; \
            } \
        } \
    } \
} while (0)

// One pipelined tile. KW_: literal vmcnt count. HBSTART_: load afr batch.
// PREF_: issue W(t+3) = W((DL_+3)&3, HB_ + ((DL_+3)>>2)).
#define TILE(DL_, HB_, KW_, HBSTART_, PREF_) do { \
    VMW(KW_); \
    STAGE_W(DL_); \
    if (HBSTART_) { LOAD_AFR(HB_); } \
    SB(); \
    if (PREF_) { LOAD_W(((DL_) + 3) & 3, (HB_) + (((DL_) + 3) >> 2)); } \
    LGKM0(); \
    __builtin_amdgcn_s_barrier(); \
    SB(); \
    if (HBSTART_) { VMW(1); } \
    COMPUTE(DL_, 1); \
} while (0)

    // ---- prologue: cmd slice, then W0..W2 (order pinned for vmcnt counts) ----
    f32x4 cv0 = *(const f32x4*)(cmd + (size_t)tid * 128 + g4);
    SB();
    LOAD_W(0, 0); SB();
    LOAD_W(1, 0); SB();
    LOAD_W(2, 0);
    VMW(3);                            // cmd returned (W0..W2 may be in flight)
    #pragma unroll
    for (int q = 0; q < 4; ++q) lcmd[q][tid] = cv0[q];

    // ---- main loop: 32 tiles ----
    for (int hb = 0; hb < 7; ++hb) {
        TILE(0, hb, 2, 1, 1);
        TILE(1, hb, 10, 0, 1);
        TILE(2, hb, 10, 0, 1);
        TILE(3, hb, 2, 0, 1);
    }
    TILE(0, 7, 2, 1, 1);               // t=28, prefetches W31
    TILE(1, 7, 10, 0, 0);              // t=29
    TILE(2, 7, 9, 0, 0);               // t=30
    TILE(3, 7, 0, 0, 0);               // t=31: fully drained after wait

    // ---- hw_b tile (g<8): h-range g*64..g*64+63, scale 1 ----
    if (g < 8) {
        f32x4 wt = *(const f32x4*)(hwbl + (size_t)(g * 64 + sh) * 512 + n0 + so);
        LOAD_AFR(g);
        VMW(0);
        #pragma unroll
        for (int q = 0; q < 4; ++q) lw[0][so + q][sh] = (__bf16)wt[q];
        LGKM0();
        __builtin_amdgcn_s_barrier();
        SB();
        COMPUTE(0, 0);
    }

    // ---- fold bias GEMM slice: Y += Σ_dl c[m,g4+dl] · hbW[g4+dl][o] ----
    #pragma unroll
    for (int dl = 0; dl < 4; ++dl) {
        float h0 = hbWl[(size_t)(g4 + dl) * 512 + n0 + l15];
        float h1 = hbWl[(size_t)(g4 + dl) * 512 + n0 + 16 + l15];
        #pragma unroll
        for (int mi = 0; mi < 4; ++mi) {
            f32x4 cv = *(const f32x4*)&lcmd[dl][m_base + mi * 16 + lg * 4];
            #pragma unroll
            for (int r = 0; r < 4; ++r) {
                Y[mi][0][r] = fmaf(cv[r], h0, Y[mi][0][r]);
                Y[mi][1][r] = fmaf(cv[r], h1, Y[mi][1][r]);
            }
        }
    }
    if (g == 0) {                      // hb_b added exactly once
        float b0 = hbbl[n0 + l15];
        float b1 = hbbl[n0 + 16 + l15];
        #pragma unroll
        for (int mi = 0; mi < 4; ++mi)
            #pragma unroll
            for (int r = 0; r < 4; ++r) {
                Y[mi][0][r] += b0;
                Y[mi][1][r] += b1;
            }
    }

    // ---- write partial[g] (exclusive slice: all m, cols n0..n0+31) ----
    float* pp = partial + (size_t)g * 262144 + n0;
    #pragma unroll
    for (int mi = 0; mi < 4; ++mi)
        #pragma unroll
        for (int r = 0; r < 4; ++r) {
            int m = m_base + mi * 16 + lg * 4 + r;
            #pragma unroll
            for (int ni = 0; ni < 2; ++ni)
                pp[(size_t)m * 512 + ni * 16 + l15] = Y[mi][ni][r];
        }

#undef LOAD_W
#undef STAGE_W
#undef LOAD_AFR
#undef COMPUTE
#undef TILE
}

// ---------------------------------------------------------------------------
// reduce: out = relu(Σ_g partial[g]); bf16 act for next layer OR f32 output.
// grid 512 (row), 256 thr: 128 lanes x f32x4 cols, 2 g-halves, LDS combine.
// ---------------------------------------------------------------------------
__global__ __launch_bounds__(256) void reduce_kernel(
    const float* __restrict__ partial,   // [32][512][512]
    __bf16* __restrict__ act_out,        // next-layer activation (or null)
    float* __restrict__ final_out)       // final output (or null)
{
    const int r = blockIdx.x, t = threadIdx.x;
    const int half = t >> 7, o4 = (t & 127) << 2;
    const float* base = partial + (size_t)half * 16 * 262144 + (size_t)r * 512 + o4;
    f32x4 s0 = (f32x4)0.f, s1 = (f32x4)0.f, s2 = (f32x4)0.f, s3 = (f32x4)0.f;
    #pragma unroll
    for (int k = 0; k < 4; ++k) {
        s0 += *(const f32x4*)(base + (size_t)k * 262144);
        s1 += *(const f32x4*)(base + (size_t)(k + 4) * 262144);
        s2 += *(const f32x4*)(base + (size_t)(k + 8) * 262144);
        s3 += *(const f32x4*)(base + (size_t)(k + 12) * 262144);
    }
    f32x4 s = (s0 + s1) + (s2 + s3);
    __shared__ f32x4 red[128];
    if (half) red[t & 127] = s;
    __syncthreads();
    if (!half) {
        s += red[t];
        #pragma unroll
        for (int j = 0; j < 4; ++j) s[j] = fmaxf(s[j], 0.f);
        if (act_out) {
            bf16x4 ov;
            #pragma unroll
            for (int j = 0; j < 4; ++j) ov[j] = (__bf16)s[j];
            *(bf16x4*)(act_out + (size_t)r * 512 + o4) = ov;
        } else {
            *(f32x4*)(final_out + (size_t)r * 512 + o4) = s;
        }
    }
}

// ---------------------------------------------------------------------------
extern "C" void kernel_launch(void* const* d_in, const int* in_sizes, int n_in,
                              void* d_out, int out_size, void* d_ws, size_t ws_size,
                              hipStream_t stream) {
    const float* state = (const float*)d_in[0];   // [512,256]
    const float* cmd   = (const float*)d_in[1];   // [512,128]
    const float* ew    = (const float*)d_in[2];   // [256,512]
    const float* eb    = (const float*)d_in[3];   // [512]
    const float* hwW   = (const float*)d_in[4];   // [2,128,262144]
    const float* hwb   = (const float*)d_in[5];   // [2,262144]
    const float* hbW   = (const float*)d_in[6];   // [2,128,512]
    const float* hbb   = (const float*)d_in[7];   // [2,512]
    float* out = (float*)d_out;

    char* ws = (char*)d_ws;
    __bf16* act0    = (__bf16*)ws;                       // 512 KB
    __bf16* act1    = (__bf16*)(ws + 512 * 1024);        // 512 KB
    float*  partial = (float*)(ws + 1024 * 1024);        // 32 MB

    embed_kernel<<<128, 512, 0, stream>>>(state, ew, eb, act0);

    // layer 0
    hyper_gemm<<<dim3(16, 32), 512, 0, stream>>>(
        hwW, hwb, cmd, hbW, hbb, act0, partial);
    reduce_kernel<<<512, 256, 0, stream>>>(partial, act1, nullptr);

    // layer 1
    hyper_gemm<<<dim3(16, 32), 512, 0, stream>>>(
        hwW + (size_t)128 * 262144, hwb + 262144, cmd,
        hbW + 128 * 512, hbb + 512, act1, partial);
    reduce_kernel<<<512, 256, 0, stream>>>(partial, nullptr, out);
}